// Round 1
// baseline (597.269 us; speedup 1.0000x reference)
//
#include <hip/hip_runtime.h>
#include <hip/hip_bf16.h>
#include <stdint.h>

#define NN 50000
#define NE 1600000
#define CIN 512
#define CH1 256
#define CH2 32

typedef __bf16 bf16_t;
typedef __attribute__((ext_vector_type(8))) __bf16 bf16x8;
typedef __attribute__((ext_vector_type(4))) float f32x4;

// ---------------- CSR build ----------------
__global__ void k_deg(const int* __restrict__ dst, int* __restrict__ deg) {
  int i = blockIdx.x * 256 + threadIdx.x;
  if (i < NE) atomicAdd(&deg[dst[i]], 1);
}

__global__ void k_scan(const int* __restrict__ deg, int* __restrict__ rowptr,
                       float* __restrict__ dinv) {
  __shared__ int lds[1024];
  __shared__ int carry_s;
  int tid = threadIdx.x;
  if (tid == 0) carry_s = 0;
  __syncthreads();
  for (int base = 0; base < NN; base += 1024) {
    int idx = base + tid;
    int v = (idx < NN) ? deg[idx] : 0;
    lds[tid] = v;
    __syncthreads();
    for (int off = 1; off < 1024; off <<= 1) {
      int t = (tid >= off) ? lds[tid - off] : 0;
      __syncthreads();
      lds[tid] += t;
      __syncthreads();
    }
    int carry = carry_s;
    if (idx < NN) {
      rowptr[idx] = carry + lds[tid] - v;          // exclusive
      dinv[idx] = 1.0f / sqrtf((float)(v + 1));    // deg includes self-loop
    }
    __syncthreads();
    if (tid == 1023) carry_s = carry + lds[1023];
    __syncthreads();
  }
  if (tid == 0) rowptr[NN] = carry_s;
}

__global__ void k_fill(const int* __restrict__ src, const int* __restrict__ dst,
                       const int* __restrict__ rowptr, int* __restrict__ cnt,
                       int* __restrict__ csr) {
  int i = blockIdx.x * 256 + threadIdx.x;
  if (i < NE) {
    int d = dst[i];
    int pos = rowptr[d] + atomicAdd(&cnt[d], 1);
    csr[pos] = src[i];
  }
}

// ---------------- dtype prep ----------------
__global__ void k_cvt_x(const float* __restrict__ x, bf16_t* __restrict__ xb) {
  int i = blockIdx.x * 256 + threadIdx.x;
  if (i >= NN * CIN / 8) return;
  int base = i * 8;
  float4 a = *(const float4*)&x[base];
  float4 b = *(const float4*)&x[base + 4];
  bf16x8 o;
  o[0] = (bf16_t)a.x; o[1] = (bf16_t)a.y; o[2] = (bf16_t)a.z; o[3] = (bf16_t)a.w;
  o[4] = (bf16_t)b.x; o[5] = (bf16_t)b.y; o[6] = (bf16_t)b.z; o[7] = (bf16_t)b.w;
  *(bf16x8*)&xb[base] = o;
}

__global__ void k_w1t(const float* __restrict__ W1, bf16_t* __restrict__ w1t) {
  int i = blockIdx.x * 256 + threadIdx.x;
  if (i < CIN * CH1) {
    int n = i >> 9;        // output channel (row of W1T)
    int k = i & 511;       // input channel
    w1t[i] = (bf16_t)W1[k * CH1 + n];
  }
}

// ---------------- GEMM1: h1' = dinv .* (x @ W1), bf16 MFMA ----------------
#define BM 128
#define BN 128
#define BK 64

__global__ __launch_bounds__(256) void k_gemm1(const bf16_t* __restrict__ A,
                                               const bf16_t* __restrict__ BT,
                                               const float* __restrict__ dinv,
                                               float* __restrict__ C) {
  __shared__ __align__(16) bf16_t lds[2][2][BM * BK];
  const int tid = threadIdx.x;
  const int lane = tid & 63;
  const int wid = tid >> 6;
  const int tm = blockIdx.x, tn = blockIdx.y;
  const int wm = wid >> 1, wn = wid & 1;

  f32x4 acc[4][4] = {};

  // stage one 128x64 bf16 tile for A and for B into lds[buf]
  // linear LDS dest (global_load_lds), inverse-swizzled global source,
  // swizzled read: phys 16B-chunk = logical chunk ^ (row&7)
  auto stage = [&](int buf, int kt) {
#pragma unroll
    for (int t = 0; t < 4; ++t) {
      int o = t * 4096 + tid * 16;   // linear byte offset in 16KB tile
      int r = o >> 7;                // row 0..127
      int cw = (o >> 4) & 7;         // physical chunk within row
      int lc = cw ^ (r & 7);         // logical chunk to fetch
      int grow = tm * BM + r;
      grow = grow < NN ? grow : NN - 1;
      const bf16_t* ga = A + (size_t)grow * CIN + kt * BK + lc * 8;
      __builtin_amdgcn_global_load_lds(
          (const __attribute__((address_space(1))) void*)ga,
          (__attribute__((address_space(3))) void*)&lds[buf][0][(t * 4096 + wid * 1024) >> 1],
          16, 0, 0);
      int gcol = tn * BN + r;        // always < 256
      const bf16_t* gb = BT + (size_t)gcol * CIN + kt * BK + lc * 8;
      __builtin_amdgcn_global_load_lds(
          (const __attribute__((address_space(1))) void*)gb,
          (__attribute__((address_space(3))) void*)&lds[buf][1][(t * 4096 + wid * 1024) >> 1],
          16, 0, 0);
    }
  };

  stage(0, 0);
  __syncthreads();
  int cur = 0;
  for (int kt = 0; kt < CIN / BK; ++kt) {
    if (kt + 1 < CIN / BK) stage(cur ^ 1, kt + 1);
#pragma unroll
    for (int ks = 0; ks < 2; ++ks) {
      bf16x8 af[4], bfr[4];
#pragma unroll
      for (int m = 0; m < 4; ++m) {
        int row = wm * 64 + m * 16 + (lane & 15);
        int kc = ks * 4 + (lane >> 4);
        af[m] = *(const bf16x8*)&lds[cur][0][row * 64 + ((kc ^ (row & 7)) << 3)];
      }
#pragma unroll
      for (int n = 0; n < 4; ++n) {
        int col = wn * 64 + n * 16 + (lane & 15);
        int kc = ks * 4 + (lane >> 4);
        bfr[n] = *(const bf16x8*)&lds[cur][1][col * 64 + ((kc ^ (col & 7)) << 3)];
      }
#pragma unroll
      for (int m = 0; m < 4; ++m)
#pragma unroll
        for (int n = 0; n < 4; ++n)
          acc[m][n] = __builtin_amdgcn_mfma_f32_16x16x32_bf16(af[m], bfr[n], acc[m][n], 0, 0, 0);
    }
    __syncthreads();
    cur ^= 1;
  }

#pragma unroll
  for (int m = 0; m < 4; ++m) {
#pragma unroll
    for (int r = 0; r < 4; ++r) {
      int grow = tm * BM + wm * 64 + m * 16 + (lane >> 4) * 4 + r;
      if (grow < NN) {
        float dv = dinv[grow];
#pragma unroll
        for (int n = 0; n < 4; ++n) {
          int gcol = tn * BN + wn * 64 + n * 16 + (lane & 15);
          C[(size_t)grow * CH1 + gcol] = dv * acc[m][n][r];
        }
      }
    }
  }
}

// ---------------- agg1 + bias + relu + GEMM2 + scale ----------------
// h2'[i] = dinv[i] * ( relu( dinv[i]*(sum_{j->i} h1'[j] + h1'[i]) + b1 ) @ W2 )
__global__ __launch_bounds__(256) void k_agg1(const float* __restrict__ h1p,
    const int* __restrict__ rowptr, const int* __restrict__ csr,
    const float* __restrict__ dinv, const float* __restrict__ b1,
    const float* __restrict__ W2, float* __restrict__ h2p) {
  const int i = blockIdx.x;
  const int c = threadIdx.x;
  const int beg = rowptr[i], end = rowptr[i + 1];
  float a0 = h1p[(size_t)i * CH1 + c], a1 = 0.f, a2 = 0.f, a3 = 0.f;  // self-loop
  int e = beg;
  for (; e + 4 <= end; e += 4) {
    int s0 = csr[e], s1 = csr[e + 1], s2 = csr[e + 2], s3 = csr[e + 3];
    a0 += h1p[(size_t)s0 * CH1 + c];
    a1 += h1p[(size_t)s1 * CH1 + c];
    a2 += h1p[(size_t)s2 * CH1 + c];
    a3 += h1p[(size_t)s3 * CH1 + c];
  }
  for (; e < end; ++e) a0 += h1p[(size_t)csr[e] * CH1 + c];
  const float di = dinv[i];
  float val = fmaxf(di * ((a0 + a1) + (a2 + a3)) + b1[c], 0.f);

  __shared__ float vals[CH1];
  __shared__ float part[8][32];
  vals[c] = val;
  __syncthreads();
  const int k = c >> 5, c2 = c & 31;
  float p = 0.f;
#pragma unroll
  for (int j = 0; j < 32; ++j)
    p += vals[k * 32 + j] * W2[(k * 32 + j) * CH2 + c2];
  part[k][c2] = p;
  __syncthreads();
  if (c < 32) {
    float h2 = 0.f;
#pragma unroll
    for (int kk = 0; kk < 8; ++kk) h2 += part[kk][c];
    h2p[i * CH2 + c] = di * h2;
  }
}

// ---------------- agg2 + bias + linear + log_softmax ----------------
__global__ __launch_bounds__(256) void k_agg2(const float* __restrict__ h2p,
    const int* __restrict__ rowptr, const int* __restrict__ csr,
    const float* __restrict__ dinv, const float* __restrict__ b2,
    const float* __restrict__ Wl, const float* __restrict__ bl,
    float* __restrict__ out) {
  const int w = threadIdx.x >> 6;
  const int lane = threadIdx.x & 63;
  const int i = blockIdx.x * 4 + w;
  if (i >= NN) return;
  const int c = lane & 31, half = lane >> 5;
  const int beg = rowptr[i], end = rowptr[i + 1];
  float acc = 0.f;
  for (int e = beg + half; e < end; e += 2)
    acc += h2p[csr[e] * CH2 + c];
  acc += __shfl_xor(acc, 32);        // combine the two edge halves
  acc += h2p[i * CH2 + c];           // self-loop
  float v = dinv[i] * acc + b2[c];   // h2a channel c
  float l = v * Wl[c * 2 + half];    // half 0 -> logit0, half 1 -> logit1
#pragma unroll
  for (int off = 1; off < 32; off <<= 1) l += __shfl_xor(l, off);
  float l0 = __shfl(l, 0) + bl[0];
  float l1 = __shfl(l, 32) + bl[1];
  if (lane < 2) {
    float m = fmaxf(l0, l1);
    float lse = m + logf(expf(l0 - m) + expf(l1 - m));
    out[i * 2 + lane] = (lane == 0 ? l0 : l1) - lse;
  }
}

extern "C" void kernel_launch(void* const* d_in, const int* in_sizes, int n_in,
                              void* d_out, int out_size, void* d_ws, size_t ws_size,
                              hipStream_t stream) {
  const float* x  = (const float*)d_in[0];
  const int*   ei = (const int*)d_in[1];
  const float* W1 = (const float*)d_in[2];
  const float* b1 = (const float*)d_in[3];
  const float* W2 = (const float*)d_in[4];
  const float* b2 = (const float*)d_in[5];
  const float* Wl = (const float*)d_in[6];
  const float* bl = (const float*)d_in[7];
  float* out = (float*)d_out;

  const int* src = ei;
  const int* dst = ei + NE;

  uint8_t* w = (uint8_t*)d_ws;
  auto alloc = [&](size_t bytes) { void* p = w; w += (bytes + 255) & ~(size_t)255; return p; };
  int*    deg    = (int*)alloc((size_t)NN * 4);
  int*    cnt    = (int*)alloc((size_t)NN * 4);
  int*    rowptr = (int*)alloc((size_t)(NN + 1) * 4);
  float*  dinv   = (float*)alloc((size_t)NN * 4);
  int*    csr    = (int*)alloc((size_t)NE * 4);
  bf16_t* xb     = (bf16_t*)alloc((size_t)NN * CIN * 2);
  bf16_t* w1t    = (bf16_t*)alloc((size_t)CIN * CH1 * 2);
  float*  h1p    = (float*)alloc((size_t)NN * CH1 * 4);
  float*  h2p    = (float*)alloc((size_t)NN * CH2 * 4);

  hipMemsetAsync(deg, 0, (size_t)NN * 4, stream);
  hipMemsetAsync(cnt, 0, (size_t)NN * 4, stream);

  k_deg<<<(NE + 255) / 256, 256, 0, stream>>>(dst, deg);
  k_scan<<<1, 1024, 0, stream>>>(deg, rowptr, dinv);
  k_fill<<<(NE + 255) / 256, 256, 0, stream>>>(src, dst, rowptr, cnt, csr);

  k_cvt_x<<<(NN * CIN / 8 + 255) / 256, 256, 0, stream>>>(x, xb);
  k_w1t<<<(CIN * CH1 + 255) / 256, 256, 0, stream>>>(W1, w1t);

  dim3 g1((NN + BM - 1) / BM, CH1 / BN);
  k_gemm1<<<g1, 256, 0, stream>>>(xb, w1t, dinv, h1p);

  k_agg1<<<NN, 256, 0, stream>>>(h1p, rowptr, csr, dinv, b1, W2, h2p);
  k_agg2<<<(NN + 3) / 4, 256, 0, stream>>>(h2p, rowptr, csr, dinv, b2, Wl, bl, out);
}

// Round 2
// 414.225 us; speedup vs baseline: 1.4419x; 1.4419x over previous
//
#include <hip/hip_runtime.h>
#include <hip/hip_bf16.h>
#include <stdint.h>

#define NN 50000
#define NE 1600000
#define CIN 512
#define CH1 256
#define CH2 32
#define NBLK ((NN + 1023) / 1024)   // 49 scan blocks

typedef __bf16 bf16_t;
typedef __attribute__((ext_vector_type(2))) __bf16 bf16x2;
typedef __attribute__((ext_vector_type(8))) __bf16 bf16x8;
typedef __attribute__((ext_vector_type(4))) float f32x4;

__device__ inline float blo(uint32_t v) { return __uint_as_float(v << 16); }
__device__ inline float bhi(uint32_t v) { return __uint_as_float(v & 0xffff0000u); }

// ---------------- CSR build ----------------
__global__ void k_deg(const int* __restrict__ dst, int* __restrict__ deg) {
  int i = blockIdx.x * 256 + threadIdx.x;
  if (i < NE) atomicAdd(&deg[dst[i]], 1);
}

__global__ __launch_bounds__(1024) void k_scan1(const int* __restrict__ deg,
    int* __restrict__ rowptr, float* __restrict__ dinv, int* __restrict__ bsum) {
  __shared__ int lds[1024];
  int tid = threadIdx.x, gid = blockIdx.x * 1024 + tid;
  int v = (gid < NN) ? deg[gid] : 0;
  int x = v;
  lds[tid] = x;
  __syncthreads();
  for (int off = 1; off < 1024; off <<= 1) {
    int t = (tid >= off) ? lds[tid - off] : 0;
    __syncthreads();
    x += t;
    lds[tid] = x;
    __syncthreads();
  }
  if (gid < NN) {
    rowptr[gid] = x - v;                        // block-local exclusive
    dinv[gid] = 1.0f / sqrtf((float)(v + 1));   // deg incl. self-loop
  }
  if (tid == 1023) bsum[blockIdx.x] = x;
}

__global__ void k_scan2(int* __restrict__ bsum, int* __restrict__ rowptr) {
  int tid = threadIdx.x;                         // 64 threads
  int v = (tid < NBLK) ? bsum[tid] : 0;
  int x = v;
  for (int off = 1; off < 64; off <<= 1) {
    int t = __shfl_up(x, off);
    if (tid >= off) x += t;
  }
  if (tid < NBLK) bsum[tid] = x - v;             // exclusive block offsets
  if (tid == 63) rowptr[NN] = x;                 // = NE
}

__global__ __launch_bounds__(1024) void k_scan3(int* __restrict__ rowptr,
                                                const int* __restrict__ bsum) {
  int gid = blockIdx.x * 1024 + threadIdx.x;
  if (gid < NN) rowptr[gid] += bsum[blockIdx.x];
}

__global__ void k_fill(const int* __restrict__ src, const int* __restrict__ dst,
                       const int* __restrict__ rowptr, int* __restrict__ cnt,
                       int* __restrict__ csr) {
  int i = blockIdx.x * 256 + threadIdx.x;
  if (i < NE) {
    int d = dst[i];
    int pos = rowptr[d] + atomicAdd(&cnt[d], 1);
    csr[pos] = src[i];
  }
}

// ---------------- weight prep (transpose to bf16) ----------------
__global__ void k_prep_w(const float* __restrict__ W1, const float* __restrict__ W2,
                         bf16_t* __restrict__ w1t, bf16_t* __restrict__ w2t) {
  int i = blockIdx.x * 256 + threadIdx.x;
  if (i < CIN * CH1) {
    int n = i >> 9, k = i & 511;
    w1t[i] = (__bf16)W1[k * CH1 + n];            // w1t[n][k]
  }
  if (i < CH1 * CH2) {
    int oc = i >> 8, k = i & 255;
    w2t[i] = (__bf16)W2[k * CH2 + oc];           // w2t[oc][k]
  }
}

// ---------------- GEMM1: h1b = bf16( dinv .* (x @ W1) ), fused fp32->bf16 ----------------
#define BM 128
#define BN 128
#define BK 64

__global__ __launch_bounds__(256) void k_gemm1(const float* __restrict__ X,
                                               const bf16_t* __restrict__ BT,
                                               const float* __restrict__ dinv,
                                               bf16_t* __restrict__ h1b) {
  __shared__ __align__(16) bf16_t ldsA[2][BM * BK];
  __shared__ __align__(16) bf16_t ldsB[2][BN * BK];
  const int tid = threadIdx.x;
  const int lane = tid & 63;
  const int wid = tid >> 6;
  const int tm = blockIdx.x, tn = blockIdx.y;
  const int wm = wid >> 1, wn = wid & 1;

  f32x4 acc[4][4] = {};
  float4 ra[4], rb[4];

  // A: reg-staged fp32 load + cvt, swizzled ds_write (rule 21: swizzle write+read)
  auto loadA = [&](int kt) {
#pragma unroll
    for (int q = 0; q < 4; ++q) {
      int idx16 = q * 256 + tid;       // 16B-chunk index in tile
      int r = idx16 >> 3, cw = idx16 & 7;
      int grow = tm * BM + r;
      grow = grow < NN ? grow : NN - 1;
      const float* ga = X + (size_t)grow * CIN + kt * BK + cw * 8;
      ra[q] = *(const float4*)ga;
      rb[q] = *(const float4*)(ga + 4);
    }
  };
  auto writeA = [&](int buf) {
#pragma unroll
    for (int q = 0; q < 4; ++q) {
      int idx16 = q * 256 + tid;
      int r = idx16 >> 3, cw = idx16 & 7;
      bf16x8 o;
      o[0] = (__bf16)ra[q].x; o[1] = (__bf16)ra[q].y;
      o[2] = (__bf16)ra[q].z; o[3] = (__bf16)ra[q].w;
      o[4] = (__bf16)rb[q].x; o[5] = (__bf16)rb[q].y;
      o[6] = (__bf16)rb[q].z; o[7] = (__bf16)rb[q].w;
      *(bf16x8*)&ldsA[buf][r * 64 + ((cw ^ (r & 7)) << 3)] = o;
    }
  };
  // B: direct global->LDS, linear dest + inverse-swizzled source
  auto stageB = [&](int buf, int kt) {
#pragma unroll
    for (int t = 0; t < 4; ++t) {
      int o = t * 4096 + tid * 16;
      int r = o >> 7, cw = (o >> 4) & 7;
      int lc = cw ^ (r & 7);
      const bf16_t* gb = BT + (size_t)(tn * BN + r) * CIN + kt * BK + lc * 8;
      __builtin_amdgcn_global_load_lds(
          (const __attribute__((address_space(1))) void*)gb,
          (__attribute__((address_space(3))) void*)&ldsB[buf][(t * 4096 + wid * 1024) >> 1],
          16, 0, 0);
    }
  };

  loadA(0);
  stageB(0, 0);
  writeA(0);
  __syncthreads();
  int cur = 0;
  for (int kt = 0; kt < CIN / BK; ++kt) {
    if (kt + 1 < CIN / BK) { loadA(kt + 1); stageB(cur ^ 1, kt + 1); }
#pragma unroll
    for (int ks = 0; ks < 2; ++ks) {
      bf16x8 af[4], bfr[4];
#pragma unroll
      for (int m = 0; m < 4; ++m) {
        int row = wm * 64 + m * 16 + (lane & 15);
        int kc = ks * 4 + (lane >> 4);
        af[m] = *(const bf16x8*)&ldsA[cur][row * 64 + ((kc ^ (row & 7)) << 3)];
      }
#pragma unroll
      for (int n = 0; n < 4; ++n) {
        int col = wn * 64 + n * 16 + (lane & 15);
        int kc = ks * 4 + (lane >> 4);
        bfr[n] = *(const bf16x8*)&ldsB[cur][col * 64 + ((kc ^ (col & 7)) << 3)];
      }
#pragma unroll
      for (int m = 0; m < 4; ++m)
#pragma unroll
        for (int n = 0; n < 4; ++n)
          acc[m][n] = __builtin_amdgcn_mfma_f32_16x16x32_bf16(af[m], bfr[n], acc[m][n], 0, 0, 0);
    }
    if (kt + 1 < CIN / BK) writeA(cur ^ 1);
    __syncthreads();
    cur ^= 1;
  }

#pragma unroll
  for (int m = 0; m < 4; ++m) {
#pragma unroll
    for (int r = 0; r < 4; ++r) {
      int grow = tm * BM + wm * 64 + m * 16 + (lane >> 4) * 4 + r;
      if (grow < NN) {
        float dv = dinv[grow];
#pragma unroll
        for (int n = 0; n < 4; ++n) {
          int gcol = tn * BN + wn * 64 + n * 16 + (lane & 15);
          h1b[(size_t)grow * CH1 + gcol] = (__bf16)(dv * acc[m][n][r]);
        }
      }
    }
  }
}

// ---------------- agg1: hr = bf16( relu( dinv_i * (sum_src h1b + h1b[i]) + b1 ) ) ----------------
__global__ __launch_bounds__(256) void k_agg1(const uint32_t* __restrict__ h1b,
    const int* __restrict__ rowptr, const int* __restrict__ csr,
    const float* __restrict__ dinv, const float* __restrict__ bias,
    uint32_t* __restrict__ hr) {
  const int i = blockIdx.x * 2 + (threadIdx.x >> 7);
  const int t = threadIdx.x & 127;           // channel pair (2t, 2t+1)
  const int lane = threadIdx.x & 63;
  const int beg = rowptr[i], end = rowptr[i + 1];

  uint32_t vs = h1b[(size_t)i * 128 + t];    // self-loop row
  float l0 = blo(vs), h0 = bhi(vs);
  float l1 = 0.f, h1 = 0.f, l2 = 0.f, h2 = 0.f, l3 = 0.f, h3 = 0.f;

  for (int base = beg; base < end; base += 64) {
    int cnt = end - base; cnt = cnt > 64 ? 64 : cnt;
    int idx = (base + lane < end) ? csr[base + lane] : 0;
    int j = 0;
    for (; j + 4 <= cnt; j += 4) {
      int p0 = __shfl(idx, j),     p1 = __shfl(idx, j + 1);
      int p2 = __shfl(idx, j + 2), p3 = __shfl(idx, j + 3);
      uint32_t v0 = h1b[(size_t)p0 * 128 + t];
      uint32_t v1 = h1b[(size_t)p1 * 128 + t];
      uint32_t v2 = h1b[(size_t)p2 * 128 + t];
      uint32_t v3 = h1b[(size_t)p3 * 128 + t];
      l0 += blo(v0); h0 += bhi(v0);
      l1 += blo(v1); h1 += bhi(v1);
      l2 += blo(v2); h2 += bhi(v2);
      l3 += blo(v3); h3 += bhi(v3);
    }
    for (; j < cnt; ++j) {
      int p = __shfl(idx, j);
      uint32_t v = h1b[(size_t)p * 128 + t];
      l0 += blo(v); h0 += bhi(v);
    }
  }
  float di = dinv[i];
  float2 bb = *(const float2*)&bias[2 * t];
  float r0 = fmaxf(di * ((l0 + l1) + (l2 + l3)) + bb.x, 0.f);
  float r1 = fmaxf(di * ((h0 + h1) + (h2 + h3)) + bb.y, 0.f);
  bf16x2 o; o[0] = (__bf16)r0; o[1] = (__bf16)r1;
  hr[(size_t)i * 128 + t] = *(uint32_t*)&o;
}

// ---------------- GEMM2 (MFMA): h2b = bf16( dinv .* (hr @ W2) ) ----------------
__global__ __launch_bounds__(256) void k_gemm2(const bf16_t* __restrict__ hr,
    const bf16_t* __restrict__ w2t, const float* __restrict__ dinv,
    bf16_t* __restrict__ h2b) {
  const int lane = threadIdx.x & 63;
  const int gw = blockIdx.x * 4 + (threadIdx.x >> 6);
  const int r0 = gw * 16;
  if (r0 >= NN) return;
  int arow = r0 + (lane & 15);
  arow = arow < NN ? arow : NN - 1;
  const int kc = lane >> 4;
  f32x4 acc0 = {}, acc1 = {};
#pragma unroll
  for (int kb = 0; kb < 8; ++kb) {
    bf16x8 a  = *(const bf16x8*)&hr [(size_t)arow * CH1 + kb * 32 + kc * 8];
    bf16x8 b0 = *(const bf16x8*)&w2t[(size_t)(lane & 15) * CH1 + kb * 32 + kc * 8];
    bf16x8 b1 = *(const bf16x8*)&w2t[(size_t)(16 + (lane & 15)) * CH1 + kb * 32 + kc * 8];
    acc0 = __builtin_amdgcn_mfma_f32_16x16x32_bf16(a, b0, acc0, 0, 0, 0);
    acc1 = __builtin_amdgcn_mfma_f32_16x16x32_bf16(a, b1, acc1, 0, 0, 0);
  }
#pragma unroll
  for (int r = 0; r < 4; ++r) {
    int rr = r0 + (lane >> 4) * 4 + r;
    if (rr < NN) {
      float dv = dinv[rr];
      h2b[(size_t)rr * CH2 + (lane & 15)]      = (__bf16)(dv * acc0[r]);
      h2b[(size_t)rr * CH2 + 16 + (lane & 15)] = (__bf16)(dv * acc1[r]);
    }
  }
}

// ---------------- agg2 + bias + linear + log_softmax ----------------
__global__ __launch_bounds__(256) void k_agg2(const bf16_t* __restrict__ h2b,
    const int* __restrict__ rowptr, const int* __restrict__ csr,
    const float* __restrict__ dinv, const float* __restrict__ b2,
    const float* __restrict__ Wl, const float* __restrict__ bl,
    float* __restrict__ out) {
  const int w = threadIdx.x >> 6;
  const int lane = threadIdx.x & 63;
  const int i = blockIdx.x * 4 + w;
  if (i >= NN) return;
  const int c = lane & 31, half = lane >> 5;
  const int beg = rowptr[i], end = rowptr[i + 1];
  float acc = 0.f;
  for (int e = beg + half; e < end; e += 2)
    acc += (float)h2b[(size_t)csr[e] * CH2 + c];
  acc += __shfl_xor(acc, 32);            // combine the two edge halves
  acc += (float)h2b[(size_t)i * CH2 + c]; // self-loop
  float v = dinv[i] * acc + b2[c];
  float l = v * Wl[c * 2 + half];        // half 0 -> logit0, half 1 -> logit1
#pragma unroll
  for (int off = 1; off < 32; off <<= 1) l += __shfl_xor(l, off);
  float l0 = __shfl(l, 0) + bl[0];
  float l1 = __shfl(l, 32) + bl[1];
  if (lane < 2) {
    float m = fmaxf(l0, l1);
    float lse = m + logf(expf(l0 - m) + expf(l1 - m));
    out[i * 2 + lane] = (lane == 0 ? l0 : l1) - lse;
  }
}

extern "C" void kernel_launch(void* const* d_in, const int* in_sizes, int n_in,
                              void* d_out, int out_size, void* d_ws, size_t ws_size,
                              hipStream_t stream) {
  const float* x  = (const float*)d_in[0];
  const int*   ei = (const int*)d_in[1];
  const float* W1 = (const float*)d_in[2];
  const float* b1 = (const float*)d_in[3];
  const float* W2 = (const float*)d_in[4];
  const float* b2 = (const float*)d_in[5];
  const float* Wl = (const float*)d_in[6];
  const float* bl = (const float*)d_in[7];
  float* out = (float*)d_out;

  const int* src = ei;
  const int* dst = ei + NE;

  uint8_t* w = (uint8_t*)d_ws;
  auto alloc = [&](size_t bytes) { void* p = w; w += (bytes + 255) & ~(size_t)255; return p; };
  int*    deg    = (int*)alloc((size_t)NN * 4);
  int*    cnt    = (int*)alloc((size_t)NN * 4);
  int*    rowptr = (int*)alloc((size_t)(NN + 1) * 4);
  float*  dinv   = (float*)alloc((size_t)NN * 4);
  int*    bsum   = (int*)alloc((size_t)64 * 4);
  int*    csr    = (int*)alloc((size_t)NE * 4);
  bf16_t* w1t    = (bf16_t*)alloc((size_t)CIN * CH1 * 2);
  bf16_t* w2t    = (bf16_t*)alloc((size_t)CH1 * CH2 * 2);
  bf16_t* h1b    = (bf16_t*)alloc((size_t)NN * CH1 * 2);
  bf16_t* hr     = (bf16_t*)alloc((size_t)NN * CH1 * 2);
  bf16_t* h2b    = (bf16_t*)alloc((size_t)NN * CH2 * 2);

  hipMemsetAsync(deg, 0, (size_t)NN * 4, stream);
  hipMemsetAsync(cnt, 0, (size_t)NN * 4, stream);

  k_deg<<<(NE + 255) / 256, 256, 0, stream>>>(dst, deg);
  k_scan1<<<NBLK, 1024, 0, stream>>>(deg, rowptr, dinv, bsum);
  k_scan2<<<1, 64, 0, stream>>>(bsum, rowptr);
  k_scan3<<<NBLK, 1024, 0, stream>>>(rowptr, bsum);
  k_fill<<<(NE + 255) / 256, 256, 0, stream>>>(src, dst, rowptr, cnt, csr);

  k_prep_w<<<(CIN * CH1 + 255) / 256, 256, 0, stream>>>(W1, W2, w1t, w2t);

  dim3 g1((NN + BM - 1) / BM, CH1 / BN);
  k_gemm1<<<g1, 256, 0, stream>>>(x, w1t, dinv, h1b);

  k_agg1<<<NN / 2, 256, 0, stream>>>((const uint32_t*)h1b, rowptr, csr, dinv, b1,
                                     (uint32_t*)hr);
  k_gemm2<<<(NN / 16 + 3) / 4, 256, 0, stream>>>(hr, w2t, dinv, h2b);
  k_agg2<<<(NN + 3) / 4, 256, 0, stream>>>(h2b, rowptr, csr, dinv, b2, Wl, bl, out);
}

// Round 3
// 243.651 us; speedup vs baseline: 2.4513x; 1.7001x over previous
//
#include <hip/hip_runtime.h>
#include <hip/hip_bf16.h>
#include <stdint.h>

#define NN 50000
#define NE 1600000
#define CIN 512
#define CH1 256
#define CH2 32

#define NBUCK 196          // ceil(50000/256) buckets of 256 nodes
#define CAP 10240          // per-bucket edge capacity (avg 8163, +20 sigma safe)
#define ECH 4096           // edges per binning block
#define NCH 391            // ceil(NE/ECH)

typedef __bf16 bf16_t;
typedef __attribute__((ext_vector_type(2))) __bf16 bf16x2;
typedef __attribute__((ext_vector_type(8))) __bf16 bf16x8;
typedef __attribute__((ext_vector_type(4))) float f32x4;

__device__ inline float blo(uint32_t v) { return __uint_as_float(v << 16); }
__device__ inline float bhi(uint32_t v) { return __uint_as_float(v & 0xffff0000u); }
__device__ inline uint32_t pk2(float a, float b) {
  bf16x2 p; p[0] = (__bf16)a; p[1] = (__bf16)b; return *(uint32_t*)&p;
}

// ============ CSR build: bucketed counting sort, no global atomics ============
// P1a: per-block histogram of dst>>8
__global__ __launch_bounds__(256) void k_hist(const int* __restrict__ dst,
                                              int* __restrict__ counts) {
  __shared__ int h[256];
  int blk = blockIdx.x, t = threadIdx.x;
  int e0 = blk * ECH;
  int ce = NE - e0; if (ce > ECH) ce = ECH;
  h[t] = 0;
  __syncthreads();
  for (int k = t; k < ce; k += 256) atomicAdd(&h[dst[e0 + k] >> 8], 1);
  __syncthreads();
  if (t < NBUCK) counts[blk * NBUCK + t] = h[t];
}

// P1b: per-bucket exclusive scan over blocks -> conflict-free write offsets
__global__ __launch_bounds__(512) void k_scanb(const int* __restrict__ counts,
                                               int* __restrict__ offs,
                                               int* __restrict__ bcnt) {
  __shared__ int l[512];
  int b = blockIdx.x, t = threadIdx.x;
  int v = (t < NCH) ? counts[t * NBUCK + b] : 0;
  int x = v;
  l[t] = x;
  __syncthreads();
  for (int off = 1; off < 512; off <<= 1) {
    int u = (t >= off) ? l[t - off] : 0;
    __syncthreads();
    x += u; l[t] = x;
    __syncthreads();
  }
  if (t < NCH) offs[t * NBUCK + b] = b * CAP + (x - v);
  if (t == 511) bcnt[b] = x;
}

// P1c: LDS-staged scatter of packed edges into per-bucket regions (coalesced writes)
__global__ __launch_bounds__(256) void k_bin(const int* __restrict__ src,
    const int* __restrict__ dst, const int* __restrict__ offs,
    uint32_t* __restrict__ binned) {
  __shared__ int h[256], lbase[256], lcnt[256], offsL[256];
  __shared__ uint32_t lstage[ECH];
  int blk = blockIdx.x, t = threadIdx.x;
  int e0 = blk * ECH;
  int ce = NE - e0; if (ce > ECH) ce = ECH;
  h[t] = 0; lcnt[t] = 0;
  if (t < NBUCK) offsL[t] = offs[blk * NBUCK + t];
  __syncthreads();
  for (int k = t; k < ce; k += 256) atomicAdd(&h[dst[e0 + k] >> 8], 1);
  __syncthreads();
  int v = h[t], x = v;
  lbase[t] = x;
  __syncthreads();
  for (int off = 1; off < 256; off <<= 1) {
    int u = (t >= off) ? lbase[t - off] : 0;
    __syncthreads();
    x += u; lbase[t] = x;
    __syncthreads();
  }
  lbase[t] = x - v;   // exclusive
  __syncthreads();
  for (int k = t; k < ce; k += 256) {
    int d = dst[e0 + k], s = src[e0 + k];
    int bkt = d >> 8;
    int p = lbase[bkt] + atomicAdd(&lcnt[bkt], 1);
    lstage[p] = ((uint32_t)bkt << 24) | ((uint32_t)(d & 255) << 16) | (uint32_t)s;
  }
  __syncthreads();
  for (int j = t; j < ce; j += 256) {
    uint32_t e = lstage[j];
    int bkt = e >> 24;
    binned[offsL[bkt] + (j - lbase[bkt])] = e & 0xffffffu >> 8 ? (e & 0x00ffffffu) : (e & 0x00ffffffu);
  }
}

// P2: one block per bucket: deg/dinv/rowptr + csr slice built in LDS, streamed out
__global__ __launch_bounds__(256) void k_build(const uint32_t* __restrict__ binned,
    const int* __restrict__ bcnt, int* __restrict__ rowptr, int* __restrict__ degg,
    float* __restrict__ dinv, int* __restrict__ csr) {
  __shared__ int hist[256], lrow[256], lcnt[256];
  __shared__ int csr_lds[CAP];
  int b = blockIdx.x, t = threadIdx.x;
  int count = bcnt[b];
  hist[t] = 0; lcnt[t] = 0;
  __syncthreads();
  const uint32_t* bb = binned + (size_t)b * CAP;
  for (int j = t; j < count; j += 256) atomicAdd(&hist[bb[j] >> 16], 1);
  __syncthreads();
  int v = hist[t], x = v;
  lrow[t] = x;
  __syncthreads();
  for (int off = 1; off < 256; off <<= 1) {
    int u = (t >= off) ? lrow[t - off] : 0;
    __syncthreads();
    x += u; lrow[t] = x;
    __syncthreads();
  }
  int excl = x - v;
  int node = b * 256 + t;
  if (node < NN) {
    rowptr[node] = b * CAP + excl;
    degg[node] = v;
    dinv[node] = 1.0f / sqrtf((float)(v + 1));   // deg incl. self-loop
  }
  lrow[t] = excl;
  __syncthreads();
  for (int j = t; j < count; j += 256) {
    uint32_t e = bb[j];
    int dl = e >> 16;
    int p = lrow[dl] + atomicAdd(&lcnt[dl], 1);
    csr_lds[p] = (int)(e & 0xffffu);
  }
  __syncthreads();
  int* co = csr + (size_t)b * CAP;
  for (int j = t; j < count; j += 256) co[j] = csr_lds[j];
}

// ---------------- weight prep (transpose to bf16) ----------------
__global__ void k_prep_w(const float* __restrict__ W1, const float* __restrict__ W2,
                         bf16_t* __restrict__ w1t, bf16_t* __restrict__ w2t) {
  int i = blockIdx.x * 256 + threadIdx.x;
  if (i < CIN * CH1) {
    int n = i >> 9, k = i & 511;
    w1t[i] = (__bf16)W1[k * CH1 + n];            // w1t[n][k]
  }
  if (i < CH1 * CH2) {
    int oc = i >> 8, k = i & 255;
    w2t[i] = (__bf16)W2[k * CH2 + oc];           // w2t[oc][k]
  }
}

// ---------------- GEMM1: h1b = bf16( dinv .* (x @ W1) ) ----------------
#define BM 128
#define BN 128
#define BK 64

__global__ __launch_bounds__(256) void k_gemm1(const float* __restrict__ X,
                                               const bf16_t* __restrict__ BT,
                                               const float* __restrict__ dinv,
                                               bf16_t* __restrict__ h1b) {
  __shared__ __align__(16) bf16_t ldsA[2][BM * BK];
  __shared__ __align__(16) bf16_t ldsB[2][BN * BK];
  const int tid = threadIdx.x;
  const int lane = tid & 63;
  const int wid = tid >> 6;
  const int tm = blockIdx.x, tn = blockIdx.y;
  const int wm = wid >> 1, wn = wid & 1;

  f32x4 acc[4][4] = {};
  float4 ra[4], rb[4];

  auto loadA = [&](int kt) {
#pragma unroll
    for (int q = 0; q < 4; ++q) {
      int idx16 = q * 256 + tid;
      int r = idx16 >> 3, cw = idx16 & 7;
      int grow = tm * BM + r;
      grow = grow < NN ? grow : NN - 1;
      const float* ga = X + (size_t)grow * CIN + kt * BK + cw * 8;
      ra[q] = *(const float4*)ga;
      rb[q] = *(const float4*)(ga + 4);
    }
  };
  auto writeA = [&](int buf) {
#pragma unroll
    for (int q = 0; q < 4; ++q) {
      int idx16 = q * 256 + tid;
      int r = idx16 >> 3, cw = idx16 & 7;
      bf16x8 o;
      o[0] = (__bf16)ra[q].x; o[1] = (__bf16)ra[q].y;
      o[2] = (__bf16)ra[q].z; o[3] = (__bf16)ra[q].w;
      o[4] = (__bf16)rb[q].x; o[5] = (__bf16)rb[q].y;
      o[6] = (__bf16)rb[q].z; o[7] = (__bf16)rb[q].w;
      *(bf16x8*)&ldsA[buf][r * 64 + ((cw ^ (r & 7)) << 3)] = o;
    }
  };
  auto stageB = [&](int buf, int kt) {
#pragma unroll
    for (int t = 0; t < 4; ++t) {
      int o = t * 4096 + tid * 16;
      int r = o >> 7, cw = (o >> 4) & 7;
      int lc = cw ^ (r & 7);
      const bf16_t* gb = BT + (size_t)(tn * BN + r) * CIN + kt * BK + lc * 8;
      __builtin_amdgcn_global_load_lds(
          (const __attribute__((address_space(1))) void*)gb,
          (__attribute__((address_space(3))) void*)&ldsB[buf][(t * 4096 + wid * 1024) >> 1],
          16, 0, 0);
    }
  };

  loadA(0);
  stageB(0, 0);
  writeA(0);
  __syncthreads();
  int cur = 0;
  for (int kt = 0; kt < CIN / BK; ++kt) {
    if (kt + 1 < CIN / BK) { loadA(kt + 1); stageB(cur ^ 1, kt + 1); }
#pragma unroll
    for (int ks = 0; ks < 2; ++ks) {
      bf16x8 af[4], bfr[4];
#pragma unroll
      for (int m = 0; m < 4; ++m) {
        int row = wm * 64 + m * 16 + (lane & 15);
        int kc = ks * 4 + (lane >> 4);
        af[m] = *(const bf16x8*)&ldsA[cur][row * 64 + ((kc ^ (row & 7)) << 3)];
      }
#pragma unroll
      for (int n = 0; n < 4; ++n) {
        int col = wn * 64 + n * 16 + (lane & 15);
        int kc = ks * 4 + (lane >> 4);
        bfr[n] = *(const bf16x8*)&ldsB[cur][col * 64 + ((kc ^ (col & 7)) << 3)];
      }
#pragma unroll
      for (int m = 0; m < 4; ++m)
#pragma unroll
        for (int n = 0; n < 4; ++n)
          acc[m][n] = __builtin_amdgcn_mfma_f32_16x16x32_bf16(af[m], bfr[n], acc[m][n], 0, 0, 0);
    }
    if (kt + 1 < CIN / BK) writeA(cur ^ 1);
    __syncthreads();
    cur ^= 1;
  }

#pragma unroll
  for (int m = 0; m < 4; ++m) {
#pragma unroll
    for (int r = 0; r < 4; ++r) {
      int grow = tm * BM + wm * 64 + m * 16 + (lane >> 4) * 4 + r;
      if (grow < NN) {
        float dv = dinv[grow];
#pragma unroll
        for (int n = 0; n < 4; ++n) {
          int gcol = tn * BN + wn * 64 + n * 16 + (lane & 15);
          h1b[(size_t)grow * CH1 + gcol] = (__bf16)(dv * acc[m][n][r]);
        }
      }
    }
  }
}

// ---------------- agg1: wave/node, dwordx4 row gathers (2 rows per instr) ----------------
#define ACC8(A, v) { A[0] += blo(v.x); A[1] += bhi(v.x); A[2] += blo(v.y); A[3] += bhi(v.y); \
                     A[4] += blo(v.z); A[5] += bhi(v.z); A[6] += blo(v.w); A[7] += bhi(v.w); }

__global__ __launch_bounds__(256) void k_agg1(const uint4* __restrict__ h1b,
    const int* __restrict__ rowptr, const int* __restrict__ degg,
    const int* __restrict__ csr, const float* __restrict__ dinv,
    const float* __restrict__ bias, uint4* __restrict__ hr) {
  const int i = blockIdx.x * 4 + (threadIdx.x >> 6);
  const int lane = threadIdx.x & 63;
  const int slot = lane & 31;      // uint4 slot: channels [slot*8, slot*8+8)
  const int grp = lane >> 5;       // which edge of the pair

  float a[8] = {}, c[8] = {};
  if (grp == 0) {                  // self-loop row
    uint4 v = h1b[(size_t)i * 32 + slot];
    ACC8(a, v);
  }
  const int beg = rowptr[i], dg = degg[i];
  for (int base = 0; base < dg; base += 64) {
    int rem = dg - base;
    int cnt = rem > 64 ? 64 : rem;
    int idx = (lane < cnt) ? csr[beg + base + lane] : 0;
    int j = 0;
    for (; j + 4 <= cnt; j += 4) {
      int s0 = __shfl(idx, j + grp);
      int s1 = __shfl(idx, j + 2 + grp);
      uint4 v0 = h1b[(size_t)s0 * 32 + slot];
      uint4 v1 = h1b[(size_t)s1 * 32 + slot];
      ACC8(a, v0);
      ACC8(c, v1);
    }
    for (; j < cnt; j += 2) {
      int e = j + grp;
      int s = __shfl(idx, e < cnt ? e : 0);
      if (e < cnt) {
        uint4 v = h1b[(size_t)s * 32 + slot];
        ACC8(a, v);
      }
    }
  }
#pragma unroll
  for (int k = 0; k < 8; ++k) {
    a[k] += c[k];
    a[k] += __shfl_xor(a[k], 32);
  }
  if (grp == 0) {
    float di = dinv[i];
    float4 b0 = *(const float4*)&bias[slot * 8];
    float4 b1 = *(const float4*)&bias[slot * 8 + 4];
    float r0 = fmaxf(di * a[0] + b0.x, 0.f), r1 = fmaxf(di * a[1] + b0.y, 0.f);
    float r2 = fmaxf(di * a[2] + b0.z, 0.f), r3 = fmaxf(di * a[3] + b0.w, 0.f);
    float r4 = fmaxf(di * a[4] + b1.x, 0.f), r5 = fmaxf(di * a[5] + b1.y, 0.f);
    float r6 = fmaxf(di * a[6] + b1.z, 0.f), r7 = fmaxf(di * a[7] + b1.w, 0.f);
    uint4 o;
    o.x = pk2(r0, r1); o.y = pk2(r2, r3); o.z = pk2(r4, r5); o.w = pk2(r6, r7);
    hr[(size_t)i * 32 + slot] = o;
  }
}

// ---------------- GEMM2 (MFMA): h2b = bf16( dinv .* (hr @ W2) ) ----------------
__global__ __launch_bounds__(256) void k_gemm2(const bf16_t* __restrict__ hr,
    const bf16_t* __restrict__ w2t, const float* __restrict__ dinv,
    bf16_t* __restrict__ h2b) {
  const int lane = threadIdx.x & 63;
  const int gw = blockIdx.x * 4 + (threadIdx.x >> 6);
  const int r0 = gw * 16;
  if (r0 >= NN) return;
  int arow = r0 + (lane & 15);
  arow = arow < NN ? arow : NN - 1;
  const int kc = lane >> 4;
  f32x4 acc0 = {}, acc1 = {};
#pragma unroll
  for (int kb = 0; kb < 8; ++kb) {
    bf16x8 a  = *(const bf16x8*)&hr [(size_t)arow * CH1 + kb * 32 + kc * 8];
    bf16x8 b0 = *(const bf16x8*)&w2t[(size_t)(lane & 15) * CH1 + kb * 32 + kc * 8];
    bf16x8 b1 = *(const bf16x8*)&w2t[(size_t)(16 + (lane & 15)) * CH1 + kb * 32 + kc * 8];
    acc0 = __builtin_amdgcn_mfma_f32_16x16x32_bf16(a, b0, acc0, 0, 0, 0);
    acc1 = __builtin_amdgcn_mfma_f32_16x16x32_bf16(a, b1, acc1, 0, 0, 0);
  }
#pragma unroll
  for (int r = 0; r < 4; ++r) {
    int rr = r0 + (lane >> 4) * 4 + r;
    if (rr < NN) {
      float dv = dinv[rr];
      h2b[(size_t)rr * CH2 + (lane & 15)]      = (__bf16)(dv * acc0[r]);
      h2b[(size_t)rr * CH2 + 16 + (lane & 15)] = (__bf16)(dv * acc1[r]);
    }
  }
}

// ---------------- agg2: wave/node, uint2 gathers (8 edges per instr) + head ----------------
__global__ __launch_bounds__(256) void k_agg2(const uint2* __restrict__ h2b,
    const int* __restrict__ rowptr, const int* __restrict__ degg,
    const int* __restrict__ csr, const float* __restrict__ dinv,
    const float* __restrict__ b2, const float* __restrict__ Wl,
    const float* __restrict__ bl, float* __restrict__ out) {
  const int i = blockIdx.x * 4 + (threadIdx.x >> 6);
  const int lane = threadIdx.x & 63;
  const int s = lane & 7;          // uint2 slot: channels [4s, 4s+4)
  const int g = lane >> 3;         // edge sub-slot 0..7

  float a[4] = {};
  if (g == 0) {                    // self-loop
    uint2 v = h2b[(size_t)i * 8 + s];
    a[0] += blo(v.x); a[1] += bhi(v.x); a[2] += blo(v.y); a[3] += bhi(v.y);
  }
  const int beg = rowptr[i], dg = degg[i];
  for (int base = 0; base < dg; base += 64) {
    int rem = dg - base;
    int cnt = rem > 64 ? 64 : rem;
    int idx = (lane < cnt) ? csr[beg + base + lane] : 0;
    int j = 0;
    for (; j + 8 <= cnt; j += 8) {
      int sr = __shfl(idx, j + g);
      uint2 v = h2b[(size_t)sr * 8 + s];
      a[0] += blo(v.x); a[1] += bhi(v.x); a[2] += blo(v.y); a[3] += bhi(v.y);
    }
    if (j < cnt) {
      int e = j + g;
      int sr = __shfl(idx, e < cnt ? e : 0);
      if (e < cnt) {
        uint2 v = h2b[(size_t)sr * 8 + s];
        a[0] += blo(v.x); a[1] += bhi(v.x); a[2] += blo(v.y); a[3] += bhi(v.y);
      }
    }
  }
#pragma unroll
  for (int k = 0; k < 4; ++k) {
    a[k] += __shfl_xor(a[k], 8);
    a[k] += __shfl_xor(a[k], 16);
    a[k] += __shfl_xor(a[k], 32);
  }
  float di = dinv[i];
  float4 bb = *(const float4*)&b2[s * 4];
  float v0 = di * a[0] + bb.x, v1 = di * a[1] + bb.y;
  float v2 = di * a[2] + bb.z, v3 = di * a[3] + bb.w;
  float2 w0 = *(const float2*)&Wl[(s * 4 + 0) * 2];
  float2 w1 = *(const float2*)&Wl[(s * 4 + 1) * 2];
  float2 w2 = *(const float2*)&Wl[(s * 4 + 2) * 2];
  float2 w3 = *(const float2*)&Wl[(s * 4 + 3) * 2];
  float l0 = v0 * w0.x + v1 * w1.x + v2 * w2.x + v3 * w3.x;
  float l1 = v0 * w0.y + v1 * w1.y + v2 * w2.y + v3 * w3.y;
#pragma unroll
  for (int off = 1; off < 8; off <<= 1) {
    l0 += __shfl_xor(l0, off);
    l1 += __shfl_xor(l1, off);
  }
  if (lane == 0) {
    l0 += bl[0]; l1 += bl[1];
    float m = fmaxf(l0, l1);
    float lse = m + logf(expf(l0 - m) + expf(l1 - m));
    float2 o; o.x = l0 - lse; o.y = l1 - lse;
    *(float2*)&out[i * 2] = o;
  }
}

extern "C" void kernel_launch(void* const* d_in, const int* in_sizes, int n_in,
                              void* d_out, int out_size, void* d_ws, size_t ws_size,
                              hipStream_t stream) {
  const float* x  = (const float*)d_in[0];
  const int*   ei = (const int*)d_in[1];
  const float* W1 = (const float*)d_in[2];
  const float* b1 = (const float*)d_in[3];
  const float* W2 = (const float*)d_in[4];
  const float* b2 = (const float*)d_in[5];
  const float* Wl = (const float*)d_in[6];
  const float* bl = (const float*)d_in[7];
  float* out = (float*)d_out;

  const int* src = ei;
  const int* dst = ei + NE;

  uint8_t* w = (uint8_t*)d_ws;
  auto alloc = [&](size_t bytes) { void* p = w; w += (bytes + 255) & ~(size_t)255; return p; };
  int*      counts = (int*)alloc((size_t)NCH * NBUCK * 4);
  int*      offs   = (int*)alloc((size_t)NCH * NBUCK * 4);
  int*      bcnt   = (int*)alloc((size_t)NBUCK * 4);
  uint32_t* binned = (uint32_t*)alloc((size_t)NBUCK * CAP * 4);
  int*      csr    = (int*)alloc((size_t)NBUCK * CAP * 4);
  int*      rowptr = (int*)alloc((size_t)NN * 4);
  int*      degg   = (int*)alloc((size_t)NN * 4);
  float*    dinv   = (float*)alloc((size_t)NN * 4);
  bf16_t*   w1t    = (bf16_t*)alloc((size_t)CIN * CH1 * 2);
  bf16_t*   w2t    = (bf16_t*)alloc((size_t)CH1 * CH2 * 2);
  bf16_t*   h1b    = (bf16_t*)alloc((size_t)NN * CH1 * 2);
  bf16_t*   hr     = (bf16_t*)alloc((size_t)NN * CH1 * 2);
  bf16_t*   h2b    = (bf16_t*)alloc((size_t)NN * CH2 * 2);

  k_hist <<<NCH, 256, 0, stream>>>(dst, counts);
  k_scanb<<<NBUCK, 512, 0, stream>>>(counts, offs, bcnt);
  k_bin  <<<NCH, 256, 0, stream>>>(src, dst, offs, binned);
  k_build<<<NBUCK, 256, 0, stream>>>(binned, bcnt, rowptr, degg, dinv, csr);

  k_prep_w<<<(CIN * CH1 + 255) / 256, 256, 0, stream>>>(W1, W2, w1t, w2t);

  dim3 g1((NN + BM - 1) / BM, CH1 / BN);
  k_gemm1<<<g1, 256, 0, stream>>>(x, w1t, dinv, h1b);

  k_agg1<<<NN / 4, 256, 0, stream>>>((const uint4*)h1b, rowptr, degg, csr, dinv, b1,
                                     (uint4*)hr);
  k_gemm2<<<(NN / 16 + 3) / 4, 256, 0, stream>>>(hr, w2t, dinv, h2b);
  k_agg2<<<NN / 4, 256, 0, stream>>>((const uint2*)h2b, rowptr, degg, csr, dinv,
                                     b2, Wl, bl, out);
}